// Round 12
// baseline (602.411 us; speedup 1.0000x reference)
//
#include <hip/hip_runtime.h>

#define N_NODES 100000
#define EDGES   1600000
#define H 64
#define OFFPAD 100352
#define SCAN_CH 512
#define SCAN_BLKS 196   // 196*512 >= N_NODES
#define NBKT 1563       // 64-node buckets
#define CHUNK 16384
#define FILL_BLKS 98    // ceil(EDGES/CHUNK)

typedef unsigned int u32;
typedef unsigned short u16;
typedef short bf16x8 __attribute__((ext_vector_type(8)));
typedef float f32x4  __attribute__((ext_vector_type(4)));

// RNE fp32 -> bf16 split: x ~= hi + lo (both bf16)
__device__ __forceinline__ void bfsplit(float x, u32& h, u32& lo) {
    union { float f; u32 u; } c; c.f = x;
    u32 hu = (c.u + 0x7fffu + ((c.u >> 16) & 1u)) & 0xffff0000u;
    h = hu >> 16;
    union { u32 u; float f; } hb; hb.u = hu;
    union { float f; u32 u; } r; r.f = x - hb.f;
    lo = (r.u + 0x7fffu + ((r.u >> 16) & 1u)) >> 16;
}

// ---------- pre-split weights into packed bf16 hi/lo (global, done once) ----------
// pa: [64][320] (w_in_a zero-padded), pu: [64][64], pb/pp: [64][128] = [Wl|Wr]
__global__ __launch_bounds__(256) void prep_weights(
    const float* __restrict__ w_a, const float* __restrict__ w_u,
    const float* __restrict__ b_wl, const float* __restrict__ b_wr,
    const float* __restrict__ p_wl, const float* __restrict__ p_wr,
    u16* __restrict__ pa_h, u16* __restrict__ pa_l,
    u16* __restrict__ pu_h, u16* __restrict__ pu_l,
    u16* __restrict__ pb_h, u16* __restrict__ pb_l,
    u16* __restrict__ pp_h, u16* __restrict__ pp_l)
{
    const int t = blockIdx.x * 256 + threadIdx.x;
    float v; u16* dh; u16* dl; int idx;
    if (t < 20480) {
        const int row = t / 320, k = t - row * 320;
        v = (k < 300) ? w_a[row * 300 + k] : 0.f;
        dh = pa_h; dl = pa_l; idx = t;
    } else if (t < 24576) {
        idx = t - 20480;
        v = w_u[idx];
        dh = pu_h; dl = pu_l;
    } else if (t < 32768) {
        idx = t - 24576;
        const int row = idx >> 7, k = idx & 127;
        v = (k < 64) ? b_wl[row * 64 + k] : b_wr[row * 64 + k - 64];
        dh = pb_h; dl = pb_l;
    } else {
        idx = t - 32768;
        const int row = idx >> 7, k = idx & 127;
        v = (k < 64) ? p_wl[row * 64 + k] : p_wr[row * 64 + k - 64];
        dh = pp_h; dl = pp_l;
    }
    u32 h, lo; bfsplit(v, h, lo);
    dh[idx] = (u16)h; dl[idx] = (u16)lo;
}

// ---------- input projection via MFMA; B-fragments direct from pre-split global ----------
template<int D, int KPAD>
__global__ __launch_bounds__(256) void proj_mfma(
    const float* __restrict__ x,
    const u16* __restrict__ wh_g, const u16* __restrict__ wl_g,
    const float* __restrict__ b, float* __restrict__ out)
{
    constexpr int NT = KPAD / 64;
    __shared__ u32 Xh[64 * 32], Xl[64 * 32];
    const int tid  = threadIdx.x;
    const int base = blockIdx.x * 64;
    const int l  = tid & 63;
    const int wv = tid >> 6;
    const int arow = wv * 16 + (l & 15);
    const int kg = l >> 4;
    f32x4 acc[4] = {};

    for (int t = 0; t < NT; ++t) {
        const int k0 = t * 64;
        for (int i = tid; i < 2048; i += 256) {
            const int row = i >> 5, u = i & 31;
            const int k = k0 + 2 * u;
            const int widx = (row << 5) | (u ^ ((row & 7) << 2));
            const int rr = min(base + row, N_NODES - 1);
            float2 v = make_float2(0.f, 0.f);
            if (k + 2 <= D) v = *(const float2*)&x[(size_t)rr * D + k];
            u32 h0, l0, h1, l1;
            bfsplit(v.x, h0, l0); bfsplit(v.y, h1, l1);
            Xh[widx] = h0 | (h1 << 16);
            Xl[widx] = l0 | (l1 << 16);
        }
        __syncthreads();
        #pragma unroll
        for (int s = 0; s < 2; ++s) {
            const int ka = (arow << 5) + ((s * 16 + kg * 4) ^ ((arow & 7) << 2));
            const bf16x8 ah = *(const bf16x8*)&Xh[ka];
            const bf16x8 al = *(const bf16x8*)&Xl[ka];
            #pragma unroll
            for (int c = 0; c < 4; ++c) {
                const int brow = c * 16 + (l & 15);
                const size_t wo = (size_t)brow * KPAD + k0 + 32 * s + 8 * kg;
                const bf16x8 bh = *(const bf16x8*)&wh_g[wo];
                const bf16x8 bl = *(const bf16x8*)&wl_g[wo];
                acc[c] = __builtin_amdgcn_mfma_f32_16x16x32_bf16(ah, bh, acc[c], 0, 0, 0);
                acc[c] = __builtin_amdgcn_mfma_f32_16x16x32_bf16(ah, bl, acc[c], 0, 0, 0);
                acc[c] = __builtin_amdgcn_mfma_f32_16x16x32_bf16(al, bh, acc[c], 0, 0, 0);
            }
        }
        __syncthreads();
    }

    const int orow0 = base + wv * 16 + (l >> 4) * 4;
    #pragma unroll
    for (int c = 0; c < 4; ++c) {
        const int col = c * 16 + (l & 15);
        const float bv = b[col];
        #pragma unroll
        for (int i = 0; i < 4; ++i) {
            const int row = orow0 + i;
            if (row < N_NODES)
                out[(size_t)row * H + col] = fmaxf(acc[c][i] + bv, 0.f);
        }
    }
}

// ---------- merged histogram (both edge types) ----------
__global__ __launch_bounds__(256) void hist2(
    const int* __restrict__ ei_p, const int* __restrict__ ei_b,
    int* __restrict__ hist_p, int* __restrict__ hist_b)
{
    const int half = EDGES / 256;
    int b = blockIdx.x;
    const int* ei; int* hist;
    if (b < half) { ei = ei_p; hist = hist_p; }
    else { b -= half; ei = ei_b; hist = hist_b; }
    int e = b * 256 + threadIdx.x;
    if (e < EDGES) atomicAdd(&hist[ei[EDGES + e]], 1);
}

// ---------- merged device-wide scan ----------
__global__ __launch_bounds__(256) void scan_partial2(
    const int* __restrict__ hist_p, const int* __restrict__ hist_b,
    int* __restrict__ bsum_p, int* __restrict__ bsum_b)
{
    __shared__ int red[256];
    int b = blockIdx.x;
    const int* hist; int* bsum;
    if (b < SCAN_BLKS) { hist = hist_p; bsum = bsum_p; }
    else { b -= SCAN_BLKS; hist = hist_b; bsum = bsum_b; }
    const int t = threadIdx.x;
    const int i0 = b * SCAN_CH + t;
    int s = 0;
    if (i0 < N_NODES) s += hist[i0];
    if (i0 + 256 < N_NODES) s += hist[i0 + 256];
    red[t] = s;
    __syncthreads();
    for (int d = 128; d > 0; d >>= 1) {
        if (t < d) red[t] += red[t + d];
        __syncthreads();
    }
    if (t == 0) bsum[b] = red[0];
}

__global__ __launch_bounds__(256) void scan_tops2(
    const int* __restrict__ bsum_p, const int* __restrict__ bsum_b,
    int* __restrict__ bpre_p, int* __restrict__ bpre_b)
{
    __shared__ int s[256];
    const int* bsum = blockIdx.x ? bsum_b : bsum_p;
    int* bpre = blockIdx.x ? bpre_b : bpre_p;
    const int t = threadIdx.x;
    const int v = (t < SCAN_BLKS) ? bsum[t] : 0;
    s[t] = v;
    __syncthreads();
    for (int d = 1; d < 256; d <<= 1) {
        int x = (t >= d) ? s[t - d] : 0;
        __syncthreads();
        s[t] += x;
        __syncthreads();
    }
    if (t < SCAN_BLKS) bpre[t] = s[t] - v;
}

__global__ __launch_bounds__(512) void scan_apply2(
    const int* __restrict__ hist_p, const int* __restrict__ hist_b,
    const int* __restrict__ bpre_p, const int* __restrict__ bpre_b,
    int* __restrict__ off_p, int* __restrict__ off_b,
    int* __restrict__ boff_p, int* __restrict__ boff_b,
    int* __restrict__ gcur_p, int* __restrict__ gcur_b)
{
    __shared__ int s[512];
    int b = blockIdx.x;
    const int* hist; const int* bpre; int* off; int* boff; int* gcur;
    if (b < SCAN_BLKS) { hist = hist_p; bpre = bpre_p; off = off_p; boff = boff_p; gcur = gcur_p; }
    else { b -= SCAN_BLKS; hist = hist_b; bpre = bpre_b; off = off_b; boff = boff_b; gcur = gcur_b; }
    const int t = threadIdx.x;
    const int i = b * SCAN_CH + t;
    const int h = (i < N_NODES) ? hist[i] : 0;
    s[t] = h;
    __syncthreads();
    for (int d = 1; d < 512; d <<= 1) {
        int x = (t >= d) ? s[t - d] : 0;
        __syncthreads();
        s[t] += x;
        __syncthreads();
    }
    if (i < N_NODES) {
        const int excl = s[t] - h + bpre[b];
        off[i] = excl;
        if ((i & 63) == 0) { boff[i >> 6] = excl; gcur[i >> 6] = excl; }
    }
    if (b == 0 && t == 0) { off[N_NODES] = EDGES; boff[NBKT] = EDGES; }
}

// ---------- level 1: chunked counting-sort into 64-node buckets ----------
__global__ __launch_bounds__(256) void sort_fill(
    const int* __restrict__ ei_p, const int* __restrict__ ei_b,
    int* __restrict__ gcur_p, int* __restrict__ gcur_b,
    int* __restrict__ raw_p, int* __restrict__ raw_b)
{
    __shared__ u32 cnt[NBKT];
    __shared__ u32 base[NBKT];
    int b = blockIdx.x;
    const int* __restrict__ ei; int* __restrict__ gcur; int* __restrict__ raw;
    if (b < FILL_BLKS) { ei = ei_p; gcur = gcur_p; raw = raw_p; }
    else { b -= FILL_BLKS; ei = ei_b; gcur = gcur_b; raw = raw_b; }
    const int tid = threadIdx.x;
    const int e0 = b * CHUNK, e1 = min(e0 + CHUNK, EDGES);

    for (int i = tid; i < NBKT; i += 256) cnt[i] = 0;
    __syncthreads();
    for (int e = e0 + tid; e < e1; e += 256)
        atomicAdd(&cnt[ei[EDGES + e] >> 6], 1u);
    __syncthreads();
    for (int i = tid; i < NBKT; i += 256) {
        const u32 c = cnt[i];
        base[i] = c ? (u32)atomicAdd(&gcur[i], (int)c) : 0u;
        cnt[i] = 0;
    }
    __syncthreads();
    for (int e = e0 + tid; e < e1; e += 256) {
        const int d = ei[EDGES + e], s = ei[e];
        const int k = d >> 6;
        const u32 pos = base[k] + atomicAdd(&cnt[k], 1u);
        raw[pos] = (s << 6) | (d & 63);
    }
}

// ---------- level 2: within-bucket scatter to per-node runs (merged both types) ----------
__global__ __launch_bounds__(256) void bucket_sort2(
    const int* __restrict__ raw_p, const int* __restrict__ raw_b,
    const int* __restrict__ off_p, const int* __restrict__ off_b,
    const int* __restrict__ boff_p, const int* __restrict__ boff_b,
    int* __restrict__ csr_p, int* __restrict__ csr_b)
{
    __shared__ int cur[64];
    int k = blockIdx.x;
    const int* raw; const int* off; const int* boff; int* csr;
    if (k < NBKT) { raw = raw_p; off = off_p; boff = boff_p; csr = csr_p; }
    else { k -= NBKT; raw = raw_b; off = off_b; boff = boff_b; csr = csr_b; }
    const int tid = threadIdx.x;
    if (tid < 64) {
        const int node = (k << 6) + tid;
        cur[tid] = (node < N_NODES) ? off[node] : EDGES;
    }
    __syncthreads();
    const int beg = boff[k], end = boff[k + 1];
    for (int e = beg + tid; e < end; e += 256) {
        const int id = raw[e];
        const int pos = atomicAdd(&cur[id & 63], 1);
        csr[pos] = id >> 6;
    }
}

// ---------- merged gather-reduce: wave per node, both aggregations ----------
__global__ __launch_bounds__(256) void gather2(
    const float* __restrict__ featA, const int* __restrict__ off_b, const int* __restrict__ csr_b,
    float* __restrict__ agg1,
    const float* __restrict__ featU, const int* __restrict__ off_p, const int* __restrict__ csr_p,
    float* __restrict__ agg2)
{
    int node = (blockIdx.x * 256 + threadIdx.x) >> 6;
    const float* feat; const int* off; const int* csr; float* agg;
    if (node < N_NODES) { feat = featA; off = off_b; csr = csr_b; agg = agg1; }
    else { node -= N_NODES; feat = featU; off = off_p; csr = csr_p; agg = agg2; }
    const int lane = threadIdx.x & 63;
    const int grp  = lane >> 4;
    const int fb   = (lane & 15) * 4;
    const int beg = off[node], end = off[node + 1];
    float4 acc = make_float4(0.f, 0.f, 0.f, 0.f);
    for (int e = beg + grp; e < end; e += 4) {
        int s = csr[e];
        const float4 v = *(const float4*)&feat[(size_t)s * H + fb];
        acc.x += v.x; acc.y += v.y; acc.z += v.z; acc.w += v.w;
    }
    #pragma unroll
    for (int m = 16; m <= 32; m <<= 1) {
        acc.x += __shfl_xor(acc.x, m, 64);
        acc.y += __shfl_xor(acc.y, m, 64);
        acc.z += __shfl_xor(acc.z, m, 64);
        acc.w += __shfl_xor(acc.w, m, 64);
    }
    const float inv = 1.0f / fmaxf((float)(end - beg), 1.0f);
    acc.x *= inv; acc.y *= inv; acc.z *= inv; acc.w *= inv;
    if (grp == 0) *(float4*)&agg[(size_t)node * H + fb] = acc;
}

// ---------- fold conv2+head ----------
__global__ __launch_bounds__(256) void fold_head(
    const float* __restrict__ w_out, const float* __restrict__ wl2,
    const float* __restrict__ wr2, const float* __restrict__ bl2,
    const float* __restrict__ b_out, float* __restrict__ headW)
{
    const int t = threadIdx.x;
    if (t < 128) {
        int o = t >> 6, j = t & 63;
        float s = 0.f;
        for (int h = 0; h < 64; ++h) s += w_out[o * 64 + h] * wl2[h * 64 + j];
        headW[o * 64 + j] = s;
    } else {
        int idx = t - 128, o = idx >> 6, j = idx & 63;
        float s = 0.f;
        for (int h = 0; h < 64; ++h) s += w_out[o * 64 + h] * wr2[h * 64 + j];
        headW[128 + o * 64 + j] = s;
    }
    if (t < 2) {
        float s = b_out[t];
        for (int h = 0; h < 64; ++h) s += w_out[t * 64 + h] * bl2[h];
        headW[256 + t] = s;
    }
}

// ---------- merged SAGE via MFMA: K=128 = [agg|xdst], W = [Wl|Wr] pre-split ----------
// First NBKT-ish blocks: user side (ZHEAD -> z). Rest: article side (in-place bufA).
#define GB 1563
__global__ __launch_bounds__(256) void sage2(
    const float* __restrict__ agg1, const float* __restrict__ xu,
    const u16* __restrict__ pb_h, const u16* __restrict__ pb_l,
    const float* __restrict__ bl_b,
    const float* __restrict__ agg2, const float* __restrict__ xa,
    const u16* __restrict__ pp_h, const u16* __restrict__ pp_l,
    const float* __restrict__ bl_p,
    const float* __restrict__ headW, float* __restrict__ z,
    float* __restrict__ outA)
{
    __shared__ u32 Ah[64 * 64], Al[64 * 64];
    __shared__ float Us[64 * 65];
    int blk = blockIdx.x;
    const bool zhead = (blk < GB);
    const float* A1; const float* A2; const u16* wh_g; const u16* wl_g; const float* bias;
    if (zhead) { A1 = agg1; A2 = xu; wh_g = pb_h; wl_g = pb_l; bias = bl_b; }
    else { blk -= GB; A1 = agg2; A2 = xa; wh_g = pp_h; wl_g = pp_l; bias = bl_p; }
    const int tid  = threadIdx.x;
    const int base = blk * 64;
    const int l  = tid & 63;
    const int wv = tid >> 6;
    const int arow = wv * 16 + (l & 15);
    const int kg = l >> 4;
    f32x4 acc[4] = {};

    for (int i = tid; i < 4096; i += 256) {
        const int row = i >> 6, u = i & 63;
        const int k = 2 * u;
        const int rr = min(base + row, N_NODES - 1);
        const float2 v = (k < 64)
            ? *(const float2*)&A1[(size_t)rr * H + k]
            : *(const float2*)&A2[(size_t)rr * H + (k - 64)];
        u32 h0, l0, h1, l1;
        bfsplit(v.x, h0, l0); bfsplit(v.y, h1, l1);
        const int widx = (row << 6) | (u ^ ((row & 7) << 2));
        Ah[widx] = h0 | (h1 << 16);
        Al[widx] = l0 | (l1 << 16);
    }
    __syncthreads();

    #pragma unroll
    for (int t = 0; t < 2; ++t) {
        #pragma unroll
        for (int s = 0; s < 2; ++s) {
            const int ka = (arow << 6) + ((t * 32 + s * 16 + kg * 4) ^ ((arow & 7) << 2));
            const bf16x8 ah = *(const bf16x8*)&Ah[ka];
            const bf16x8 al = *(const bf16x8*)&Al[ka];
            #pragma unroll
            for (int c = 0; c < 4; ++c) {
                const int brow = c * 16 + (l & 15);
                const size_t wo = (size_t)brow * 128 + t * 64 + 32 * s + 8 * kg;
                const bf16x8 bh = *(const bf16x8*)&wh_g[wo];
                const bf16x8 bl = *(const bf16x8*)&wl_g[wo];
                acc[c] = __builtin_amdgcn_mfma_f32_16x16x32_bf16(ah, bh, acc[c], 0, 0, 0);
                acc[c] = __builtin_amdgcn_mfma_f32_16x16x32_bf16(ah, bl, acc[c], 0, 0, 0);
                acc[c] = __builtin_amdgcn_mfma_f32_16x16x32_bf16(al, bh, acc[c], 0, 0, 0);
            }
        }
    }

    const int r0 = wv * 16 + (l >> 4) * 4;
    if (!zhead) {
        #pragma unroll
        for (int c = 0; c < 4; ++c) {
            const int col = c * 16 + (l & 15);
            const float bv = bias[col];
            #pragma unroll
            for (int i = 0; i < 4; ++i) {
                const int row = base + r0 + i;
                if (row < N_NODES)
                    outA[(size_t)row * H + col] = fmaxf(acc[c][i] + bv, 0.f);
            }
        }
    } else {
        #pragma unroll
        for (int c = 0; c < 4; ++c) {
            const int col = c * 16 + (l & 15);
            const float bv = bias[col];
            #pragma unroll
            for (int i = 0; i < 4; ++i)
                Us[(r0 + i) * 65 + col] = fmaxf(acc[c][i] + bv, 0.f);
        }
        __syncthreads();
        if (tid < 128) {
            const int r = tid & 63, o = tid >> 6;
            const int row = base + r;
            if (row < N_NODES) {
                float v = 0.f;
                for (int k = 0; k < 64; ++k)
                    v += Us[r * 65 + k] * headW[o * 64 + k];
                z[(size_t)row * 2 + o] = v;
            }
        }
    }
}

// ---------- final: out[n] = mean_p(z) + a1[n] @ Wr'^T + b' ----------
__global__ __launch_bounds__(256) void final_head(
    const int* __restrict__ off, const int* __restrict__ csr,
    const float* __restrict__ z, const float* __restrict__ a1,
    const float* __restrict__ headW, float* __restrict__ out)
{
    const int node = (blockIdx.x * 256 + threadIdx.x) >> 6;
    const int lane = threadIdx.x & 63;
    const int beg = off[node], end = off[node + 1];
    float z0 = 0.f, z1 = 0.f;
    for (int e = beg + lane; e < end; e += 64) {
        int s = csr[e];
        const float2 zv = *(const float2*)&z[(size_t)s * 2];
        z0 += zv.x; z1 += zv.y;
    }
    const float av = a1[(size_t)node * H + lane];
    float p0 = av * headW[128 + lane];
    float p1 = av * headW[192 + lane];
    #pragma unroll
    for (int m = 1; m <= 32; m <<= 1) {
        z0 += __shfl_xor(z0, m, 64);
        z1 += __shfl_xor(z1, m, 64);
        p0 += __shfl_xor(p0, m, 64);
        p1 += __shfl_xor(p1, m, 64);
    }
    if (lane == 0) {
        const float inv = 1.0f / fmaxf((float)(end - beg), 1.0f);
        float2 o;
        o.x = z0 * inv + p0 + headW[256];
        o.y = z1 * inv + p1 + headW[257];
        *(float2*)&out[(size_t)node * 2] = o;
    }
}

extern "C" void kernel_launch(void* const* d_in, const int* in_sizes, int n_in,
                              void* d_out, int out_size, void* d_ws, size_t ws_size,
                              hipStream_t stream) {
    const float* x_a    = (const float*)d_in[0];
    const float* x_u    = (const float*)d_in[1];
    const int*   ei_p   = (const int*)d_in[2];
    const int*   ei_b   = (const int*)d_in[3];
    const float* w_in_a = (const float*)d_in[4];
    const float* b_in_a = (const float*)d_in[5];
    const float* w_in_u = (const float*)d_in[6];
    const float* b_in_u = (const float*)d_in[7];
    const float* c1p_wl = (const float*)d_in[8];
    const float* c1p_bl = (const float*)d_in[9];
    const float* c1p_wr = (const float*)d_in[10];
    const float* c1b_wl = (const float*)d_in[11];
    const float* c1b_bl = (const float*)d_in[12];
    const float* c1b_wr = (const float*)d_in[13];
    const float* c2p_wl = (const float*)d_in[14];
    const float* c2p_bl = (const float*)d_in[15];
    const float* c2p_wr = (const float*)d_in[16];
    const float* w_out  = (const float*)d_in[20];
    const float* b_out  = (const float*)d_in[21];

    const size_t NF = (size_t)N_NODES * H;
    float* bufA  = (float*)d_ws;
    float* bufU  = bufA + NF;
    float* agg1  = bufU + NF;          // raw CSR scratch aliases agg1 (pre-gather only)
    float* agg2  = agg1 + NF;
    float* z     = agg2 + NF;
    float* headW = z + 2 * N_NODES;
    int* off_p  = (int*)(headW + 512);
    int* off_b  = off_p + OFFPAD;
    int* boff_p = off_b + OFFPAD;
    int* boff_b = boff_p + 2048;
    int* gcur_p = boff_b + 2048;
    int* gcur_b = gcur_p + 2048;
    int* hist_p = gcur_b + 2048;
    int* hist_b = hist_p + OFFPAD;
    int* bsum_p = hist_b + OFFPAD;
    int* bsum_b = bsum_p + 256;
    int* bpre_p = bsum_b + 256;
    int* bpre_b = bpre_p + 256;
    int* csr_p  = bpre_b + 256;
    int* csr_b  = csr_p + EDGES;
    u16* pa_h   = (u16*)(csr_b + EDGES);
    u16* pa_l   = pa_h + 20480;
    u16* pu_h   = pa_l + 20480;
    u16* pu_l   = pu_h + 4096;
    u16* pb_h   = pu_l + 4096;
    u16* pb_l   = pb_h + 8192;
    u16* pp_h   = pb_l + 8192;
    u16* pp_l   = pp_h + 8192;
    int* raw_p  = (int*)agg1;          // 2*EDGES ints fit in 2 x NF floats
    int* raw_b  = raw_p + EDGES;

    const dim3 blk(256);
    const int grid_edge = EDGES / 256;           // 6250
    const int grid_gemm = (N_NODES + 63) / 64;   // 1563

    // --- weight prep + head fold (independent of graph work) ---
    prep_weights<<<160, blk, 0, stream>>>(
        w_in_a, w_in_u, c1b_wl, c1b_wr, c1p_wl, c1p_wr,
        pa_h, pa_l, pu_h, pu_l, pb_h, pb_l, pp_h, pp_l);
    fold_head<<<1, blk, 0, stream>>>(w_out, c2p_wl, c2p_wr, c2p_bl, b_out, headW);

    // --- two-level counting sort ---
    hipMemsetAsync(hist_p, 0, 2 * OFFPAD * sizeof(int), stream);
    hist2<<<2 * grid_edge, blk, 0, stream>>>(ei_p, ei_b, hist_p, hist_b);
    scan_partial2<<<2 * SCAN_BLKS, blk, 0, stream>>>(hist_p, hist_b, bsum_p, bsum_b);
    scan_tops2<<<2, blk, 0, stream>>>(bsum_p, bsum_b, bpre_p, bpre_b);
    scan_apply2<<<2 * SCAN_BLKS, 512, 0, stream>>>(
        hist_p, hist_b, bpre_p, bpre_b, off_p, off_b, boff_p, boff_b, gcur_p, gcur_b);
    sort_fill<<<2 * FILL_BLKS, blk, 0, stream>>>(ei_p, ei_b, gcur_p, gcur_b, raw_p, raw_b);
    bucket_sort2<<<2 * NBKT, blk, 0, stream>>>(
        raw_p, raw_b, off_p, off_b, boff_p, boff_b, csr_p, csr_b);

    // --- input projections (MFMA, pre-split weights) ---
    proj_mfma<300, 320><<<grid_gemm, blk, 0, stream>>>(x_a, pa_h, pa_l, b_in_a, bufA);
    proj_mfma<64, 64>  <<<grid_gemm, blk, 0, stream>>>(x_u, pu_h, pu_l, b_in_u, bufU);

    // --- both aggregations in one launch ---
    gather2<<<2 * 25000, blk, 0, stream>>>(
        bufA, off_b, csr_b, agg1, bufU, off_p, csr_p, agg2);

    // --- both SAGE updates in one launch (user side fuses folded head -> z) ---
    sage2<<<2 * grid_gemm, blk, 0, stream>>>(
        agg1, bufU, pb_h, pb_l, c1b_bl,
        agg2, bufA, pp_h, pp_l, c1p_bl,
        headW, z, bufA);

    // --- final 2-dim aggregation + head ---
    final_head<<<25000, blk, 0, stream>>>(off_p, csr_p, z, bufA, headW, (float*)d_out);

    (void)in_sizes; (void)n_in; (void)out_size; (void)ws_size;
}

// Round 13
// 412.636 us; speedup vs baseline: 1.4599x; 1.4599x over previous
//
#include <hip/hip_runtime.h>

#define N_NODES 100000
#define EDGES   1600000
#define H 64
#define OFFPAD 100352
#define NBKT 1563       // 64-node buckets
#define CHUNK 16384
#define FILL_BLKS 98    // ceil(EDGES/CHUNK)

typedef unsigned int u32;
typedef short bf16x8 __attribute__((ext_vector_type(8)));
typedef float f32x4  __attribute__((ext_vector_type(4)));

// RNE fp32 -> bf16 split: x ~= hi + lo (both bf16)
__device__ __forceinline__ void bfsplit(float x, u32& h, u32& lo) {
    union { float f; u32 u; } c; c.f = x;
    u32 hu = (c.u + 0x7fffu + ((c.u >> 16) & 1u)) & 0xffff0000u;
    h = hu >> 16;
    union { u32 u; float f; } hb; hb.u = hu;
    union { float f; u32 u; } r; r.f = x - hb.f;
    lo = (r.u + 0x7fffu + ((r.u >> 16) & 1u)) >> 16;
}

// ---------- pre-split weights into PACKED u32 (2 bf16 per word), done once ----------
// pa: [64][160] u32 (w_in_a, K padded 300->320), pu: [64][32], pb/pp: [64][64] = [Wl|Wr]
__global__ __launch_bounds__(256) void prep_weights(
    const float* __restrict__ w_a, const float* __restrict__ w_u,
    const float* __restrict__ b_wl, const float* __restrict__ b_wr,
    const float* __restrict__ p_wl, const float* __restrict__ p_wr,
    u32* __restrict__ pa_h, u32* __restrict__ pa_l,
    u32* __restrict__ pu_h, u32* __restrict__ pu_l,
    u32* __restrict__ pb_h, u32* __restrict__ pb_l,
    u32* __restrict__ pp_h, u32* __restrict__ pp_l)
{
    const int t = blockIdx.x * 256 + threadIdx.x;   // 80*256 = 20480 total
    float v0 = 0.f, v1 = 0.f; u32* dh; u32* dl; int idx;
    if (t < 10240) {
        const int row = t / 160, u = t - row * 160, k = 2 * u;
        if (k < 300)     v0 = w_a[row * 300 + k];
        if (k + 1 < 300) v1 = w_a[row * 300 + k + 1];
        dh = pa_h; dl = pa_l; idx = t;
    } else if (t < 12288) {
        idx = t - 10240;
        const int row = idx >> 5, u = idx & 31, k = 2 * u;
        v0 = w_u[row * 64 + k]; v1 = w_u[row * 64 + k + 1];
        dh = pu_h; dl = pu_l;
    } else if (t < 16384) {
        idx = t - 12288;
        const int row = idx >> 6, u = idx & 63, k = 2 * u;
        if (k < 64) { v0 = b_wl[row * 64 + k];      v1 = b_wl[row * 64 + k + 1]; }
        else        { v0 = b_wr[row * 64 + k - 64]; v1 = b_wr[row * 64 + k - 63]; }
        dh = pb_h; dl = pb_l;
    } else {
        idx = t - 16384;
        const int row = idx >> 6, u = idx & 63, k = 2 * u;
        if (k < 64) { v0 = p_wl[row * 64 + k];      v1 = p_wl[row * 64 + k + 1]; }
        else        { v0 = p_wr[row * 64 + k - 64]; v1 = p_wr[row * 64 + k - 63]; }
        dh = pp_h; dl = pp_l;
    }
    u32 h0, l0, h1, l1; bfsplit(v0, h0, l0); bfsplit(v1, h1, l1);
    dh[idx] = h0 | (h1 << 16);
    dl[idx] = l0 | (l1 << 16);
}

// ---------- input projection via MFMA; X bfsplit->LDS, W copied pre-split->LDS ----------
template<int D, int KPAD>
__global__ __launch_bounds__(256) void proj_mfma(
    const float* __restrict__ x,
    const u32* __restrict__ wh_g, const u32* __restrict__ wl_g,
    const float* __restrict__ b, float* __restrict__ out)
{
    constexpr int NT = KPAD / 64;
    __shared__ u32 Xh[64 * 32], Xl[64 * 32], Wh[64 * 32], Wl[64 * 32];
    const int tid  = threadIdx.x;
    const int base = blockIdx.x * 64;
    const int l  = tid & 63;
    const int wv = tid >> 6;
    const int arow = wv * 16 + (l & 15);
    const int kg = l >> 4;
    f32x4 acc[4] = {};

    for (int t = 0; t < NT; ++t) {
        const int k0 = t * 64;
        for (int i = tid; i < 2048; i += 256) {
            const int row = i >> 5, u = i & 31;
            const int k = k0 + 2 * u;
            const int widx = (row << 5) | (u ^ ((row & 7) << 2));
            const int rr = min(base + row, N_NODES - 1);
            float2 v = make_float2(0.f, 0.f);
            if (k + 2 <= D) v = *(const float2*)&x[(size_t)rr * D + k];
            u32 h0, l0, h1, l1;
            bfsplit(v.x, h0, l0); bfsplit(v.y, h1, l1);
            Xh[widx] = h0 | (h1 << 16);
            Xl[widx] = l0 | (l1 << 16);
            // W tile: straight copy (pre-split), same swizzle
            Wh[widx] = wh_g[row * (KPAD / 2) + (k0 >> 1) + u];
            Wl[widx] = wl_g[row * (KPAD / 2) + (k0 >> 1) + u];
        }
        __syncthreads();
        #pragma unroll
        for (int s = 0; s < 2; ++s) {
            const int ka = (arow << 5) + ((s * 16 + kg * 4) ^ ((arow & 7) << 2));
            const bf16x8 ah = *(const bf16x8*)&Xh[ka];
            const bf16x8 al = *(const bf16x8*)&Xl[ka];
            #pragma unroll
            for (int c = 0; c < 4; ++c) {
                const int brow = c * 16 + (l & 15);
                const int kb = (brow << 5) + ((s * 16 + kg * 4) ^ ((brow & 7) << 2));
                const bf16x8 bh = *(const bf16x8*)&Wh[kb];
                const bf16x8 bl = *(const bf16x8*)&Wl[kb];
                acc[c] = __builtin_amdgcn_mfma_f32_16x16x32_bf16(ah, bh, acc[c], 0, 0, 0);
                acc[c] = __builtin_amdgcn_mfma_f32_16x16x32_bf16(ah, bl, acc[c], 0, 0, 0);
                acc[c] = __builtin_amdgcn_mfma_f32_16x16x32_bf16(al, bh, acc[c], 0, 0, 0);
            }
        }
        __syncthreads();
    }

    const int orow0 = base + wv * 16 + (l >> 4) * 4;
    #pragma unroll
    for (int c = 0; c < 4; ++c) {
        const int col = c * 16 + (l & 15);
        const float bv = b[col];
        #pragma unroll
        for (int i = 0; i < 4; ++i) {
            const int row = orow0 + i;
            if (row < N_NODES)
                out[(size_t)row * H + col] = fmaxf(acc[c][i] + bv, 0.f);
        }
    }
}

// ---------- bucket-level histogram (LDS-binned per chunk; 6 KB bins) ----------
__global__ __launch_bounds__(256) void bucket_hist(
    const int* __restrict__ ei_p, const int* __restrict__ ei_b,
    int* __restrict__ bh_p, int* __restrict__ bh_b)
{
    __shared__ int cnt[NBKT];
    int b = blockIdx.x;
    const int* ei; int* bh;
    if (b < FILL_BLKS) { ei = ei_p; bh = bh_p; }
    else { b -= FILL_BLKS; ei = ei_b; bh = bh_b; }
    const int tid = threadIdx.x;
    for (int i = tid; i < NBKT; i += 256) cnt[i] = 0;
    __syncthreads();
    const int e0 = b * CHUNK, e1 = min(e0 + CHUNK, EDGES);
    for (int e = e0 + tid; e < e1; e += 256)
        atomicAdd(&cnt[ei[EDGES + e] >> 6], 1);
    __syncthreads();
    for (int i = tid; i < NBKT; i += 256)
        if (cnt[i]) atomicAdd(&bh[i], cnt[i]);
}

// ---------- scan over NBKT bucket counts -> boff/gcur (one block per type) ----------
__global__ __launch_bounds__(256) void scan_nbkt(
    const int* __restrict__ bh_p, const int* __restrict__ bh_b,
    int* __restrict__ boff_p, int* __restrict__ boff_b,
    int* __restrict__ gcur_p, int* __restrict__ gcur_b)
{
    __shared__ int part[256];
    const int* bh = blockIdx.x ? bh_b : bh_p;
    int* boff = blockIdx.x ? boff_b : boff_p;
    int* gcur = blockIdx.x ? gcur_b : gcur_p;
    const int t = threadIdx.x;
    const int CH = 7;                 // 256*7 >= NBKT
    const int base = t * CH;
    int s = 0;
    for (int j = 0; j < CH; ++j) { int i = base + j; if (i < NBKT) s += bh[i]; }
    part[t] = s;
    __syncthreads();
    for (int d = 1; d < 256; d <<= 1) {
        int x = (t >= d) ? part[t - d] : 0;
        __syncthreads();
        part[t] += x;
        __syncthreads();
    }
    int run = part[t] - s;
    for (int j = 0; j < CH; ++j) {
        int i = base + j;
        if (i < NBKT) { boff[i] = run; gcur[i] = run; run += bh[i]; }
    }
    if (t == 0) boff[NBKT] = EDGES;
}

// ---------- level 1: chunked counting-sort into 64-node buckets ----------
__global__ __launch_bounds__(256) void sort_fill(
    const int* __restrict__ ei_p, const int* __restrict__ ei_b,
    int* __restrict__ gcur_p, int* __restrict__ gcur_b,
    int* __restrict__ raw_p, int* __restrict__ raw_b)
{
    __shared__ u32 cnt[NBKT];
    __shared__ u32 base[NBKT];
    int b = blockIdx.x;
    const int* __restrict__ ei; int* __restrict__ gcur; int* __restrict__ raw;
    if (b < FILL_BLKS) { ei = ei_p; gcur = gcur_p; raw = raw_p; }
    else { b -= FILL_BLKS; ei = ei_b; gcur = gcur_b; raw = raw_b; }
    const int tid = threadIdx.x;
    const int e0 = b * CHUNK, e1 = min(e0 + CHUNK, EDGES);

    for (int i = tid; i < NBKT; i += 256) cnt[i] = 0;
    __syncthreads();
    for (int e = e0 + tid; e < e1; e += 256)
        atomicAdd(&cnt[ei[EDGES + e] >> 6], 1u);
    __syncthreads();
    for (int i = tid; i < NBKT; i += 256) {
        const u32 c = cnt[i];
        base[i] = c ? (u32)atomicAdd(&gcur[i], (int)c) : 0u;
        cnt[i] = 0;
    }
    __syncthreads();
    for (int e = e0 + tid; e < e1; e += 256) {
        const int d = ei[EDGES + e], s = ei[e];
        const int k = d >> 6;
        const u32 pos = base[k] + atomicAdd(&cnt[k], 1u);
        raw[pos] = (s << 6) | (d & 63);
    }
}

// ---------- level 2: per-node off[] derivation + scatter to per-node runs ----------
__global__ __launch_bounds__(256) void bucket_sort2(
    const int* __restrict__ raw_p, const int* __restrict__ raw_b,
    const int* __restrict__ boff_p, const int* __restrict__ boff_b,
    int* __restrict__ off_p, int* __restrict__ off_b,
    int* __restrict__ csr_p, int* __restrict__ csr_b)
{
    __shared__ int cnt[64];
    __shared__ int cur[64];
    int k = blockIdx.x;
    const int* raw; const int* boff; int* off; int* csr;
    if (k < NBKT) { raw = raw_p; boff = boff_p; off = off_p; csr = csr_p; }
    else { k -= NBKT; raw = raw_b; boff = boff_b; off = off_b; csr = csr_b; }
    const int tid = threadIdx.x;
    if (tid < 64) cnt[tid] = 0;
    __syncthreads();
    const int beg = boff[k], end = boff[k + 1];
    for (int e = beg + tid; e < end; e += 256)
        atomicAdd(&cnt[raw[e] & 63], 1);
    __syncthreads();
    if (tid == 0) {
        int run = beg;
        for (int i = 0; i < 64; ++i) { cur[i] = run; run += cnt[i]; }
    }
    __syncthreads();
    if (tid < 64) off[(k << 6) + tid] = cur[tid];   // node<=100031 < OFFPAD; off[N_NODES]=EDGES falls out
    __syncthreads();
    for (int e = beg + tid; e < end; e += 256) {
        const int id = raw[e];
        const int pos = atomicAdd(&cur[id & 63], 1);
        csr[pos] = id >> 6;
    }
}

// ---------- merged gather-reduce: wave per node, both aggregations ----------
__global__ __launch_bounds__(256) void gather2(
    const float* __restrict__ featA, const int* __restrict__ off_b, const int* __restrict__ csr_b,
    float* __restrict__ agg1,
    const float* __restrict__ featU, const int* __restrict__ off_p, const int* __restrict__ csr_p,
    float* __restrict__ agg2)
{
    int node = (blockIdx.x * 256 + threadIdx.x) >> 6;
    const float* feat; const int* off; const int* csr; float* agg;
    if (node < N_NODES) { feat = featA; off = off_b; csr = csr_b; agg = agg1; }
    else { node -= N_NODES; feat = featU; off = off_p; csr = csr_p; agg = agg2; }
    const int lane = threadIdx.x & 63;
    const int grp  = lane >> 4;
    const int fb   = (lane & 15) * 4;
    const int beg = off[node], end = off[node + 1];
    float4 acc = make_float4(0.f, 0.f, 0.f, 0.f);
    for (int e = beg + grp; e < end; e += 4) {
        int s = csr[e];
        const float4 v = *(const float4*)&feat[(size_t)s * H + fb];
        acc.x += v.x; acc.y += v.y; acc.z += v.z; acc.w += v.w;
    }
    #pragma unroll
    for (int m = 16; m <= 32; m <<= 1) {
        acc.x += __shfl_xor(acc.x, m, 64);
        acc.y += __shfl_xor(acc.y, m, 64);
        acc.z += __shfl_xor(acc.z, m, 64);
        acc.w += __shfl_xor(acc.w, m, 64);
    }
    const float inv = 1.0f / fmaxf((float)(end - beg), 1.0f);
    acc.x *= inv; acc.y *= inv; acc.z *= inv; acc.w *= inv;
    if (grp == 0) *(float4*)&agg[(size_t)node * H + fb] = acc;
}

// ---------- fold conv2+head ----------
__global__ __launch_bounds__(256) void fold_head(
    const float* __restrict__ w_out, const float* __restrict__ wl2,
    const float* __restrict__ wr2, const float* __restrict__ bl2,
    const float* __restrict__ b_out, float* __restrict__ headW)
{
    const int t = threadIdx.x;
    if (t < 128) {
        int o = t >> 6, j = t & 63;
        float s = 0.f;
        for (int h = 0; h < 64; ++h) s += w_out[o * 64 + h] * wl2[h * 64 + j];
        headW[o * 64 + j] = s;
    } else {
        int idx = t - 128, o = idx >> 6, j = idx & 63;
        float s = 0.f;
        for (int h = 0; h < 64; ++h) s += w_out[o * 64 + h] * wr2[h * 64 + j];
        headW[128 + o * 64 + j] = s;
    }
    if (t < 2) {
        float s = b_out[t];
        for (int h = 0; h < 64; ++h) s += w_out[t * 64 + h] * bl2[h];
        headW[256 + t] = s;
    }
}

// ---------- merged SAGE via MFMA: K=128 = [agg|xdst]; W tiles staged pre-split ----------
#define GB 1563
__global__ __launch_bounds__(256) void sage2(
    const float* __restrict__ agg1, const float* __restrict__ xu,
    const u32* __restrict__ pb_h, const u32* __restrict__ pb_l,
    const float* __restrict__ bl_b,
    const float* __restrict__ agg2, const float* __restrict__ xa,
    const u32* __restrict__ pp_h, const u32* __restrict__ pp_l,
    const float* __restrict__ bl_p,
    const float* __restrict__ headW, float* __restrict__ z,
    float* __restrict__ outA)
{
    __shared__ u32 Ah[4096], Al[4096];                    // [64 rows][64 u32] full K=128
    union ShW { u32 w[4096]; float us[64 * 65]; };        // W tile (hi|lo) aliases Us epilogue
    __shared__ ShW shw;
    int blk = blockIdx.x;
    const bool zhead = (blk < GB);
    const float* A1; const float* A2; const u32* wh_g; const u32* wl_g; const float* bias;
    if (zhead) { A1 = agg1; A2 = xu; wh_g = pb_h; wl_g = pb_l; bias = bl_b; }
    else { blk -= GB; A1 = agg2; A2 = xa; wh_g = pp_h; wl_g = pp_l; bias = bl_p; }
    const int tid  = threadIdx.x;
    const int base = blk * 64;
    const int l  = tid & 63;
    const int wv = tid >> 6;
    const int arow = wv * 16 + (l & 15);
    const int kg = l >> 4;
    f32x4 acc[4] = {};

    for (int i = tid; i < 4096; i += 256) {
        const int row = i >> 6, u = i & 63;
        const int k = 2 * u;
        const int rr = min(base + row, N_NODES - 1);
        const float2 v = (k < 64)
            ? *(const float2*)&A1[(size_t)rr * H + k]
            : *(const float2*)&A2[(size_t)rr * H + (k - 64)];
        u32 h0, l0, h1, l1;
        bfsplit(v.x, h0, l0); bfsplit(v.y, h1, l1);
        const int widx = (row << 6) | (u ^ ((row & 7) << 2));
        Ah[widx] = h0 | (h1 << 16);
        Al[widx] = l0 | (l1 << 16);
    }

    #pragma unroll
    for (int t = 0; t < 2; ++t) {
        // stage W tile t (k in [64t, 64t+64)): straight pre-split copy, swizzled
        for (int i = tid; i < 2048; i += 256) {
            const int row = i >> 5, u = i & 31;
            const int widx = (row << 5) | (u ^ ((row & 7) << 2));
            shw.w[widx]        = wh_g[row * 64 + t * 32 + u];
            shw.w[2048 + widx] = wl_g[row * 64 + t * 32 + u];
        }
        __syncthreads();
        #pragma unroll
        for (int s = 0; s < 2; ++s) {
            const int ka = (arow << 6) + ((t * 32 + s * 16 + kg * 4) ^ ((arow & 7) << 2));
            const bf16x8 ah = *(const bf16x8*)&Ah[ka];
            const bf16x8 al = *(const bf16x8*)&Al[ka];
            #pragma unroll
            for (int c = 0; c < 4; ++c) {
                const int brow = c * 16 + (l & 15);
                const int kb = (brow << 5) + ((s * 16 + kg * 4) ^ ((brow & 7) << 2));
                const bf16x8 bh = *(const bf16x8*)&shw.w[kb];
                const bf16x8 bl = *(const bf16x8*)&shw.w[2048 + kb];
                acc[c] = __builtin_amdgcn_mfma_f32_16x16x32_bf16(ah, bh, acc[c], 0, 0, 0);
                acc[c] = __builtin_amdgcn_mfma_f32_16x16x32_bf16(ah, bl, acc[c], 0, 0, 0);
                acc[c] = __builtin_amdgcn_mfma_f32_16x16x32_bf16(al, bh, acc[c], 0, 0, 0);
            }
        }
        __syncthreads();
    }

    const int r0 = wv * 16 + (l >> 4) * 4;
    if (!zhead) {
        #pragma unroll
        for (int c = 0; c < 4; ++c) {
            const int col = c * 16 + (l & 15);
            const float bv = bias[col];
            #pragma unroll
            for (int i = 0; i < 4; ++i) {
                const int row = base + r0 + i;
                if (row < N_NODES)
                    outA[(size_t)row * H + col] = fmaxf(acc[c][i] + bv, 0.f);
            }
        }
    } else {
        #pragma unroll
        for (int c = 0; c < 4; ++c) {
            const int col = c * 16 + (l & 15);
            const float bv = bias[col];
            #pragma unroll
            for (int i = 0; i < 4; ++i)
                shw.us[(r0 + i) * 65 + col] = fmaxf(acc[c][i] + bv, 0.f);
        }
        __syncthreads();
        if (tid < 128) {
            const int r = tid & 63, o = tid >> 6;
            const int row = base + r;
            if (row < N_NODES) {
                float v = 0.f;
                for (int k = 0; k < 64; ++k)
                    v += shw.us[r * 65 + k] * headW[o * 64 + k];
                z[(size_t)row * 2 + o] = v;
            }
        }
    }
}

// ---------- final: out[n] = mean_p(z) + a1[n] @ Wr'^T + b' ----------
__global__ __launch_bounds__(256) void final_head(
    const int* __restrict__ off, const int* __restrict__ csr,
    const float* __restrict__ z, const float* __restrict__ a1,
    const float* __restrict__ headW, float* __restrict__ out)
{
    const int node = (blockIdx.x * 256 + threadIdx.x) >> 6;
    const int lane = threadIdx.x & 63;
    const int beg = off[node], end = off[node + 1];
    float z0 = 0.f, z1 = 0.f;
    for (int e = beg + lane; e < end; e += 64) {
        int s = csr[e];
        const float2 zv = *(const float2*)&z[(size_t)s * 2];
        z0 += zv.x; z1 += zv.y;
    }
    const float av = a1[(size_t)node * H + lane];
    float p0 = av * headW[128 + lane];
    float p1 = av * headW[192 + lane];
    #pragma unroll
    for (int m = 1; m <= 32; m <<= 1) {
        z0 += __shfl_xor(z0, m, 64);
        z1 += __shfl_xor(z1, m, 64);
        p0 += __shfl_xor(p0, m, 64);
        p1 += __shfl_xor(p1, m, 64);
    }
    if (lane == 0) {
        const float inv = 1.0f / fmaxf((float)(end - beg), 1.0f);
        float2 o;
        o.x = z0 * inv + p0 + headW[256];
        o.y = z1 * inv + p1 + headW[257];
        *(float2*)&out[(size_t)node * 2] = o;
    }
}

extern "C" void kernel_launch(void* const* d_in, const int* in_sizes, int n_in,
                              void* d_out, int out_size, void* d_ws, size_t ws_size,
                              hipStream_t stream) {
    const float* x_a    = (const float*)d_in[0];
    const float* x_u    = (const float*)d_in[1];
    const int*   ei_p   = (const int*)d_in[2];
    const int*   ei_b   = (const int*)d_in[3];
    const float* w_in_a = (const float*)d_in[4];
    const float* b_in_a = (const float*)d_in[5];
    const float* w_in_u = (const float*)d_in[6];
    const float* b_in_u = (const float*)d_in[7];
    const float* c1p_wl = (const float*)d_in[8];
    const float* c1p_bl = (const float*)d_in[9];
    const float* c1p_wr = (const float*)d_in[10];
    const float* c1b_wl = (const float*)d_in[11];
    const float* c1b_bl = (const float*)d_in[12];
    const float* c1b_wr = (const float*)d_in[13];
    const float* c2p_wl = (const float*)d_in[14];
    const float* c2p_bl = (const float*)d_in[15];
    const float* c2p_wr = (const float*)d_in[16];
    const float* w_out  = (const float*)d_in[20];
    const float* b_out  = (const float*)d_in[21];

    const size_t NF = (size_t)N_NODES * H;
    float* bufA  = (float*)d_ws;
    float* bufU  = bufA + NF;
    float* agg1  = bufU + NF;          // raw CSR scratch aliases agg1/agg2 (pre-gather only)
    float* agg2  = agg1 + NF;
    float* z     = agg2 + NF;
    float* headW = z + 2 * N_NODES;
    int* bh_p   = (int*)(headW + 512); // bucket hists (contiguous for one memset)
    int* bh_b   = bh_p + 2048;
    int* boff_p = bh_b + 2048;
    int* boff_b = boff_p + 2048;
    int* gcur_p = boff_b + 2048;
    int* gcur_b = gcur_p + 2048;
    int* off_p  = gcur_b + 2048;
    int* off_b  = off_p + OFFPAD;
    int* csr_p  = off_b + OFFPAD;
    int* csr_b  = csr_p + EDGES;
    u32* pa_h   = (u32*)(csr_b + EDGES);
    u32* pa_l   = pa_h + 10240;
    u32* pu_h   = pa_l + 10240;
    u32* pu_l   = pu_h + 2048;
    u32* pb_h   = pu_l + 2048;
    u32* pb_l   = pb_h + 4096;
    u32* pp_h   = pb_l + 4096;
    u32* pp_l   = pp_h + 4096;
    int* raw_p  = (int*)agg1;          // 2*EDGES ints fit in agg1 (NF floats)
    int* raw_b  = raw_p + EDGES;

    const dim3 blk(256);
    const int grid_gemm = (N_NODES + 63) / 64;   // 1563

    // --- weight prep + head fold ---
    prep_weights<<<80, blk, 0, stream>>>(
        w_in_a, w_in_u, c1b_wl, c1b_wr, c1p_wl, c1p_wr,
        pa_h, pa_l, pu_h, pu_l, pb_h, pb_l, pp_h, pp_l);
    fold_head<<<1, blk, 0, stream>>>(w_out, c2p_wl, c2p_wr, c2p_bl, b_out, headW);

    // --- two-level counting sort (bucket-granular hist only; per-node off derived in L2 sort) ---
    hipMemsetAsync(bh_p, 0, 2 * 2048 * sizeof(int), stream);
    bucket_hist<<<2 * FILL_BLKS, blk, 0, stream>>>(ei_p, ei_b, bh_p, bh_b);
    scan_nbkt<<<2, blk, 0, stream>>>(bh_p, bh_b, boff_p, boff_b, gcur_p, gcur_b);
    sort_fill<<<2 * FILL_BLKS, blk, 0, stream>>>(ei_p, ei_b, gcur_p, gcur_b, raw_p, raw_b);
    bucket_sort2<<<2 * NBKT, blk, 0, stream>>>(
        raw_p, raw_b, boff_p, boff_b, off_p, off_b, csr_p, csr_b);

    // --- input projections (MFMA, pre-split weights staged to LDS) ---
    proj_mfma<300, 320><<<grid_gemm, blk, 0, stream>>>(x_a, pa_h, pa_l, b_in_a, bufA);
    proj_mfma<64, 64>  <<<grid_gemm, blk, 0, stream>>>(x_u, pu_h, pu_l, b_in_u, bufU);

    // --- both aggregations in one launch ---
    gather2<<<2 * 25000, blk, 0, stream>>>(
        bufA, off_b, csr_b, agg1, bufU, off_p, csr_p, agg2);

    // --- both SAGE updates in one launch (user side fuses folded head -> z) ---
    sage2<<<2 * grid_gemm, blk, 0, stream>>>(
        agg1, bufU, pb_h, pb_l, c1b_bl,
        agg2, bufA, pp_h, pp_l, c1p_bl,
        headW, z, bufA);

    // --- final 2-dim aggregation + head ---
    final_head<<<25000, blk, 0, stream>>>(off_p, csr_p, z, bufA, headW, (float*)d_out);

    (void)in_sizes; (void)n_in; (void)out_size; (void)ws_size;
}

// Round 14
// 388.216 us; speedup vs baseline: 1.5517x; 1.0629x over previous
//
#include <hip/hip_runtime.h>

#define N_NODES 100000
#define EDGES   1600000
#define H 64
#define OFFPAD 100352
#define NBKT 1563       // 64-node buckets
#define CHUNK 16384
#define FILL_BLKS 98    // ceil(EDGES/CHUNK)

typedef unsigned int u32;
typedef unsigned short u16;
typedef short bf16x8 __attribute__((ext_vector_type(8)));
typedef float f32x4  __attribute__((ext_vector_type(4)));

// RNE fp32 -> bf16 split: x ~= hi + lo (both bf16)
__device__ __forceinline__ void bfsplit(float x, u32& h, u32& lo) {
    union { float f; u32 u; } c; c.f = x;
    u32 hu = (c.u + 0x7fffu + ((c.u >> 16) & 1u)) & 0xffff0000u;
    h = hu >> 16;
    union { u32 u; float f; } hb; hb.u = hu;
    union { float f; u32 u; } r; r.f = x - hb.f;
    lo = (r.u + 0x7fffu + ((r.u >> 16) & 1u)) >> 16;
}
__device__ __forceinline__ u16 bfrne(float x) {
    union { float f; u32 u; } c; c.f = x;
    return (u16)((c.u + 0x7fffu + ((c.u >> 16) & 1u)) >> 16);
}
__device__ __forceinline__ float bflo(u32 w)  { union { u32 u; float f; } c; c.u = w << 16; return c.f; }
__device__ __forceinline__ float bfhi(u32 w)  { union { u32 u; float f; } c; c.u = w & 0xffff0000u; return c.f; }

// ---------- pre-split weights into PACKED u32 (2 bf16 per word), done once ----------
__global__ __launch_bounds__(256) void prep_weights(
    const float* __restrict__ w_a, const float* __restrict__ w_u,
    const float* __restrict__ b_wl, const float* __restrict__ b_wr,
    const float* __restrict__ p_wl, const float* __restrict__ p_wr,
    u32* __restrict__ pa_h, u32* __restrict__ pa_l,
    u32* __restrict__ pu_h, u32* __restrict__ pu_l,
    u32* __restrict__ pb_h, u32* __restrict__ pb_l,
    u32* __restrict__ pp_h, u32* __restrict__ pp_l)
{
    const int t = blockIdx.x * 256 + threadIdx.x;   // 80*256 = 20480 total
    float v0 = 0.f, v1 = 0.f; u32* dh; u32* dl; int idx;
    if (t < 10240) {
        const int row = t / 160, u = t - row * 160, k = 2 * u;
        if (k < 300)     v0 = w_a[row * 300 + k];
        if (k + 1 < 300) v1 = w_a[row * 300 + k + 1];
        dh = pa_h; dl = pa_l; idx = t;
    } else if (t < 12288) {
        idx = t - 10240;
        const int row = idx >> 5, u = idx & 31, k = 2 * u;
        v0 = w_u[row * 64 + k]; v1 = w_u[row * 64 + k + 1];
        dh = pu_h; dl = pu_l;
    } else if (t < 16384) {
        idx = t - 12288;
        const int row = idx >> 6, u = idx & 63, k = 2 * u;
        if (k < 64) { v0 = b_wl[row * 64 + k];      v1 = b_wl[row * 64 + k + 1]; }
        else        { v0 = b_wr[row * 64 + k - 64]; v1 = b_wr[row * 64 + k - 63]; }
        dh = pb_h; dl = pb_l;
    } else {
        idx = t - 16384;
        const int row = idx >> 6, u = idx & 63, k = 2 * u;
        if (k < 64) { v0 = p_wl[row * 64 + k];      v1 = p_wl[row * 64 + k + 1]; }
        else        { v0 = p_wr[row * 64 + k - 64]; v1 = p_wr[row * 64 + k - 63]; }
        dh = pp_h; dl = pp_l;
    }
    u32 h0, l0, h1, l1; bfsplit(v0, h0, l0); bfsplit(v1, h1, l1);
    dh[idx] = h0 | (h1 << 16);
    dl[idx] = l0 | (l1 << 16);
}

// ---------- input projection via MFMA; writes fp32 + packed-bf16 shadow ----------
template<int D, int KPAD>
__global__ __launch_bounds__(256) void proj_mfma(
    const float* __restrict__ x,
    const u32* __restrict__ wh_g, const u32* __restrict__ wl_g,
    const float* __restrict__ b, float* __restrict__ out, u16* __restrict__ outb)
{
    constexpr int NT = KPAD / 64;
    __shared__ u32 Xh[64 * 32], Xl[64 * 32], Wh[64 * 32], Wl[64 * 32];
    const int tid  = threadIdx.x;
    const int base = blockIdx.x * 64;
    const int l  = tid & 63;
    const int wv = tid >> 6;
    const int arow = wv * 16 + (l & 15);
    const int kg = l >> 4;
    f32x4 acc[4] = {};

    for (int t = 0; t < NT; ++t) {
        const int k0 = t * 64;
        for (int i = tid; i < 2048; i += 256) {
            const int row = i >> 5, u = i & 31;
            const int k = k0 + 2 * u;
            const int widx = (row << 5) | (u ^ ((row & 7) << 2));
            const int rr = min(base + row, N_NODES - 1);
            float2 v = make_float2(0.f, 0.f);
            if (k + 2 <= D) v = *(const float2*)&x[(size_t)rr * D + k];
            u32 h0, l0, h1, l1;
            bfsplit(v.x, h0, l0); bfsplit(v.y, h1, l1);
            Xh[widx] = h0 | (h1 << 16);
            Xl[widx] = l0 | (l1 << 16);
            Wh[widx] = wh_g[row * (KPAD / 2) + (k0 >> 1) + u];
            Wl[widx] = wl_g[row * (KPAD / 2) + (k0 >> 1) + u];
        }
        __syncthreads();
        #pragma unroll
        for (int s = 0; s < 2; ++s) {
            const int ka = (arow << 5) + ((s * 16 + kg * 4) ^ ((arow & 7) << 2));
            const bf16x8 ah = *(const bf16x8*)&Xh[ka];
            const bf16x8 al = *(const bf16x8*)&Xl[ka];
            #pragma unroll
            for (int c = 0; c < 4; ++c) {
                const int brow = c * 16 + (l & 15);
                const int kb = (brow << 5) + ((s * 16 + kg * 4) ^ ((brow & 7) << 2));
                const bf16x8 bh = *(const bf16x8*)&Wh[kb];
                const bf16x8 bl = *(const bf16x8*)&Wl[kb];
                acc[c] = __builtin_amdgcn_mfma_f32_16x16x32_bf16(ah, bh, acc[c], 0, 0, 0);
                acc[c] = __builtin_amdgcn_mfma_f32_16x16x32_bf16(ah, bl, acc[c], 0, 0, 0);
                acc[c] = __builtin_amdgcn_mfma_f32_16x16x32_bf16(al, bh, acc[c], 0, 0, 0);
            }
        }
        __syncthreads();
    }

    const int orow0 = base + wv * 16 + (l >> 4) * 4;
    #pragma unroll
    for (int c = 0; c < 4; ++c) {
        const int col = c * 16 + (l & 15);
        const float bv = b[col];
        #pragma unroll
        for (int i = 0; i < 4; ++i) {
            const int row = orow0 + i;
            if (row < N_NODES) {
                const float v = fmaxf(acc[c][i] + bv, 0.f);
                out[(size_t)row * H + col] = v;
                outb[(size_t)row * H + col] = bfrne(v);
            }
        }
    }
}

// ---------- bucket-level histogram (LDS-binned per chunk) ----------
__global__ __launch_bounds__(256) void bucket_hist(
    const int* __restrict__ ei_p, const int* __restrict__ ei_b,
    int* __restrict__ bh_p, int* __restrict__ bh_b)
{
    __shared__ int cnt[NBKT];
    int b = blockIdx.x;
    const int* ei; int* bh;
    if (b < FILL_BLKS) { ei = ei_p; bh = bh_p; }
    else { b -= FILL_BLKS; ei = ei_b; bh = bh_b; }
    const int tid = threadIdx.x;
    for (int i = tid; i < NBKT; i += 256) cnt[i] = 0;
    __syncthreads();
    const int e0 = b * CHUNK, e1 = min(e0 + CHUNK, EDGES);
    for (int e = e0 + tid; e < e1; e += 256)
        atomicAdd(&cnt[ei[EDGES + e] >> 6], 1);
    __syncthreads();
    for (int i = tid; i < NBKT; i += 256)
        if (cnt[i]) atomicAdd(&bh[i], cnt[i]);
}

// ---------- scan over NBKT bucket counts -> boff/gcur ----------
__global__ __launch_bounds__(256) void scan_nbkt(
    const int* __restrict__ bh_p, const int* __restrict__ bh_b,
    int* __restrict__ boff_p, int* __restrict__ boff_b,
    int* __restrict__ gcur_p, int* __restrict__ gcur_b)
{
    __shared__ int part[256];
    const int* bh = blockIdx.x ? bh_b : bh_p;
    int* boff = blockIdx.x ? boff_b : boff_p;
    int* gcur = blockIdx.x ? gcur_b : gcur_p;
    const int t = threadIdx.x;
    const int CH = 7;
    const int base = t * CH;
    int s = 0;
    for (int j = 0; j < CH; ++j) { int i = base + j; if (i < NBKT) s += bh[i]; }
    part[t] = s;
    __syncthreads();
    for (int d = 1; d < 256; d <<= 1) {
        int x = (t >= d) ? part[t - d] : 0;
        __syncthreads();
        part[t] += x;
        __syncthreads();
    }
    int run = part[t] - s;
    for (int j = 0; j < CH; ++j) {
        int i = base + j;
        if (i < NBKT) { boff[i] = run; gcur[i] = run; run += bh[i]; }
    }
    if (t == 0) boff[NBKT] = EDGES;
}

// ---------- level 1: chunked counting-sort into 64-node buckets ----------
__global__ __launch_bounds__(256) void sort_fill(
    const int* __restrict__ ei_p, const int* __restrict__ ei_b,
    int* __restrict__ gcur_p, int* __restrict__ gcur_b,
    int* __restrict__ raw_p, int* __restrict__ raw_b)
{
    __shared__ u32 cnt[NBKT];
    __shared__ u32 base[NBKT];
    int b = blockIdx.x;
    const int* __restrict__ ei; int* __restrict__ gcur; int* __restrict__ raw;
    if (b < FILL_BLKS) { ei = ei_p; gcur = gcur_p; raw = raw_p; }
    else { b -= FILL_BLKS; ei = ei_b; gcur = gcur_b; raw = raw_b; }
    const int tid = threadIdx.x;
    const int e0 = b * CHUNK, e1 = min(e0 + CHUNK, EDGES);

    for (int i = tid; i < NBKT; i += 256) cnt[i] = 0;
    __syncthreads();
    for (int e = e0 + tid; e < e1; e += 256)
        atomicAdd(&cnt[ei[EDGES + e] >> 6], 1u);
    __syncthreads();
    for (int i = tid; i < NBKT; i += 256) {
        const u32 c = cnt[i];
        base[i] = c ? (u32)atomicAdd(&gcur[i], (int)c) : 0u;
        cnt[i] = 0;
    }
    __syncthreads();
    for (int e = e0 + tid; e < e1; e += 256) {
        const int d = ei[EDGES + e], s = ei[e];
        const int k = d >> 6;
        const u32 pos = base[k] + atomicAdd(&cnt[k], 1u);
        raw[pos] = (s << 6) | (d & 63);
    }
}

// ---------- level 2: per-node off[] derivation + scatter to per-node runs ----------
__global__ __launch_bounds__(256) void bucket_sort2(
    const int* __restrict__ raw_p, const int* __restrict__ raw_b,
    const int* __restrict__ boff_p, const int* __restrict__ boff_b,
    int* __restrict__ off_p, int* __restrict__ off_b,
    int* __restrict__ csr_p, int* __restrict__ csr_b)
{
    __shared__ int cnt[64];
    __shared__ int cur[64];
    int k = blockIdx.x;
    const int* raw; const int* boff; int* off; int* csr;
    if (k < NBKT) { raw = raw_p; boff = boff_p; off = off_p; csr = csr_p; }
    else { k -= NBKT; raw = raw_b; boff = boff_b; off = off_b; csr = csr_b; }
    const int tid = threadIdx.x;
    if (tid < 64) cnt[tid] = 0;
    __syncthreads();
    const int beg = boff[k], end = boff[k + 1];
    for (int e = beg + tid; e < end; e += 256)
        atomicAdd(&cnt[raw[e] & 63], 1);
    __syncthreads();
    if (tid == 0) {
        int run = beg;
        for (int i = 0; i < 64; ++i) { cur[i] = run; run += cnt[i]; }
    }
    __syncthreads();
    if (tid < 64) off[(k << 6) + tid] = cur[tid];
    __syncthreads();
    for (int e = beg + tid; e < end; e += 256) {
        const int id = raw[e];
        const int pos = atomicAdd(&cur[id & 63], 1);
        csr[pos] = id >> 6;
    }
}

// ---------- gather-reduce from bf16 shadow: wave per node, 8 edges in flight ----------
__global__ __launch_bounds__(256) void gather_bf16(
    const u16* __restrict__ featb, const int* __restrict__ off,
    const int* __restrict__ csr, float* __restrict__ agg)
{
    const int node = (blockIdx.x * 256 + threadIdx.x) >> 6;
    const int lane = threadIdx.x & 63;
    const int grp  = lane >> 3;          // 8 edges in flight
    const int q    = lane & 7;           // owns u32s [4q..4q+3] = feats [8q..8q+7]
    const u32* fb = (const u32*)featb;   // row stride 32 u32
    const int beg = off[node], end = off[node + 1];
    float a0=0.f,a1=0.f,a2=0.f,a3=0.f,a4=0.f,a5=0.f,a6=0.f,a7=0.f;
    for (int e = beg + grp; e < end; e += 8) {
        const int s = csr[e];
        const uint4 v = *(const uint4*)&fb[((size_t)s << 5) + (q << 2)];
        a0 += bflo(v.x); a1 += bfhi(v.x);
        a2 += bflo(v.y); a3 += bfhi(v.y);
        a4 += bflo(v.z); a5 += bfhi(v.z);
        a6 += bflo(v.w); a7 += bfhi(v.w);
    }
    #pragma unroll
    for (int m = 8; m <= 32; m <<= 1) {
        a0 += __shfl_xor(a0, m, 64); a1 += __shfl_xor(a1, m, 64);
        a2 += __shfl_xor(a2, m, 64); a3 += __shfl_xor(a3, m, 64);
        a4 += __shfl_xor(a4, m, 64); a5 += __shfl_xor(a5, m, 64);
        a6 += __shfl_xor(a6, m, 64); a7 += __shfl_xor(a7, m, 64);
    }
    if (grp == 0) {
        const float inv = 1.0f / fmaxf((float)(end - beg), 1.0f);
        float4 o0 = make_float4(a0 * inv, a1 * inv, a2 * inv, a3 * inv);
        float4 o1 = make_float4(a4 * inv, a5 * inv, a6 * inv, a7 * inv);
        *(float4*)&agg[(size_t)node * H + 8 * q]     = o0;
        *(float4*)&agg[(size_t)node * H + 8 * q + 4] = o1;
    }
}

// ---------- fold conv2+head ----------
__global__ __launch_bounds__(256) void fold_head(
    const float* __restrict__ w_out, const float* __restrict__ wl2,
    const float* __restrict__ wr2, const float* __restrict__ bl2,
    const float* __restrict__ b_out, float* __restrict__ headW)
{
    const int t = threadIdx.x;
    if (t < 128) {
        int o = t >> 6, j = t & 63;
        float s = 0.f;
        for (int h = 0; h < 64; ++h) s += w_out[o * 64 + h] * wl2[h * 64 + j];
        headW[o * 64 + j] = s;
    } else {
        int idx = t - 128, o = idx >> 6, j = idx & 63;
        float s = 0.f;
        for (int h = 0; h < 64; ++h) s += w_out[o * 64 + h] * wr2[h * 64 + j];
        headW[128 + o * 64 + j] = s;
    }
    if (t < 2) {
        float s = b_out[t];
        for (int h = 0; h < 64; ++h) s += w_out[t * 64 + h] * bl2[h];
        headW[256 + t] = s;
    }
}

// ---------- SAGE via MFMA: K=128 = [agg|xdst]; W tiles staged pre-split ----------
template<bool ZHEAD>
__global__ __launch_bounds__(256) void sage_mfma(
    const float* __restrict__ A1, const float* __restrict__ A2,
    const u32* __restrict__ wh_g, const u32* __restrict__ wl_g,
    const float* __restrict__ bias,
    const float* __restrict__ headW, float* __restrict__ z,
    float* __restrict__ outA)
{
    __shared__ u32 Ah[4096], Al[4096];
    union ShW { u32 w[4096]; float us[64 * 65]; };
    __shared__ ShW shw;
    const int tid  = threadIdx.x;
    const int base = blockIdx.x * 64;
    const int l  = tid & 63;
    const int wv = tid >> 6;
    const int arow = wv * 16 + (l & 15);
    const int kg = l >> 4;
    f32x4 acc[4] = {};

    for (int i = tid; i < 4096; i += 256) {
        const int row = i >> 6, u = i & 63;
        const int k = 2 * u;
        const int rr = min(base + row, N_NODES - 1);
        const float2 v = (k < 64)
            ? *(const float2*)&A1[(size_t)rr * H + k]
            : *(const float2*)&A2[(size_t)rr * H + (k - 64)];
        u32 h0, l0, h1, l1;
        bfsplit(v.x, h0, l0); bfsplit(v.y, h1, l1);
        const int widx = (row << 6) | (u ^ ((row & 7) << 2));
        Ah[widx] = h0 | (h1 << 16);
        Al[widx] = l0 | (l1 << 16);
    }

    #pragma unroll
    for (int t = 0; t < 2; ++t) {
        for (int i = tid; i < 2048; i += 256) {
            const int row = i >> 5, u = i & 31;
            const int widx = (row << 5) | (u ^ ((row & 7) << 2));
            shw.w[widx]        = wh_g[row * 64 + t * 32 + u];
            shw.w[2048 + widx] = wl_g[row * 64 + t * 32 + u];
        }
        __syncthreads();
        #pragma unroll
        for (int s = 0; s < 2; ++s) {
            const int ka = (arow << 6) + ((t * 32 + s * 16 + kg * 4) ^ ((arow & 7) << 2));
            const bf16x8 ah = *(const bf16x8*)&Ah[ka];
            const bf16x8 al = *(const bf16x8*)&Al[ka];
            #pragma unroll
            for (int c = 0; c < 4; ++c) {
                const int brow = c * 16 + (l & 15);
                const int kb = (brow << 5) + ((s * 16 + kg * 4) ^ ((brow & 7) << 2));
                const bf16x8 bh = *(const bf16x8*)&shw.w[kb];
                const bf16x8 bl = *(const bf16x8*)&shw.w[2048 + kb];
                acc[c] = __builtin_amdgcn_mfma_f32_16x16x32_bf16(ah, bh, acc[c], 0, 0, 0);
                acc[c] = __builtin_amdgcn_mfma_f32_16x16x32_bf16(ah, bl, acc[c], 0, 0, 0);
                acc[c] = __builtin_amdgcn_mfma_f32_16x16x32_bf16(al, bh, acc[c], 0, 0, 0);
            }
        }
        __syncthreads();
    }

    const int r0 = wv * 16 + (l >> 4) * 4;
    if (!ZHEAD) {
        #pragma unroll
        for (int c = 0; c < 4; ++c) {
            const int col = c * 16 + (l & 15);
            const float bv = bias[col];
            #pragma unroll
            for (int i = 0; i < 4; ++i) {
                const int row = base + r0 + i;
                if (row < N_NODES)
                    outA[(size_t)row * H + col] = fmaxf(acc[c][i] + bv, 0.f);
            }
        }
    } else {
        #pragma unroll
        for (int c = 0; c < 4; ++c) {
            const int col = c * 16 + (l & 15);
            const float bv = bias[col];
            #pragma unroll
            for (int i = 0; i < 4; ++i)
                shw.us[(r0 + i) * 65 + col] = fmaxf(acc[c][i] + bv, 0.f);
        }
        __syncthreads();
        if (tid < 128) {
            const int r = tid & 63, o = tid >> 6;
            const int row = base + r;
            if (row < N_NODES) {
                float v = 0.f;
                for (int k = 0; k < 64; ++k)
                    v += shw.us[r * 65 + k] * headW[o * 64 + k];
                z[(size_t)row * 2 + o] = v;
            }
        }
    }
}

// ---------- final: out[n] = mean_p(z) + a1[n] @ Wr'^T + b' ----------
__global__ __launch_bounds__(256) void final_head(
    const int* __restrict__ off, const int* __restrict__ csr,
    const float* __restrict__ z, const float* __restrict__ a1,
    const float* __restrict__ headW, float* __restrict__ out)
{
    const int node = (blockIdx.x * 256 + threadIdx.x) >> 6;
    const int lane = threadIdx.x & 63;
    const int beg = off[node], end = off[node + 1];
    float z0 = 0.f, z1 = 0.f;
    for (int e = beg + lane; e < end; e += 64) {
        int s = csr[e];
        const float2 zv = *(const float2*)&z[(size_t)s * 2];
        z0 += zv.x; z1 += zv.y;
    }
    const float av = a1[(size_t)node * H + lane];
    float p0 = av * headW[128 + lane];
    float p1 = av * headW[192 + lane];
    #pragma unroll
    for (int m = 1; m <= 32; m <<= 1) {
        z0 += __shfl_xor(z0, m, 64);
        z1 += __shfl_xor(z1, m, 64);
        p0 += __shfl_xor(p0, m, 64);
        p1 += __shfl_xor(p1, m, 64);
    }
    if (lane == 0) {
        const float inv = 1.0f / fmaxf((float)(end - beg), 1.0f);
        float2 o;
        o.x = z0 * inv + p0 + headW[256];
        o.y = z1 * inv + p1 + headW[257];
        *(float2*)&out[(size_t)node * 2] = o;
    }
}

extern "C" void kernel_launch(void* const* d_in, const int* in_sizes, int n_in,
                              void* d_out, int out_size, void* d_ws, size_t ws_size,
                              hipStream_t stream) {
    const float* x_a    = (const float*)d_in[0];
    const float* x_u    = (const float*)d_in[1];
    const int*   ei_p   = (const int*)d_in[2];
    const int*   ei_b   = (const int*)d_in[3];
    const float* w_in_a = (const float*)d_in[4];
    const float* b_in_a = (const float*)d_in[5];
    const float* w_in_u = (const float*)d_in[6];
    const float* b_in_u = (const float*)d_in[7];
    const float* c1p_wl = (const float*)d_in[8];
    const float* c1p_bl = (const float*)d_in[9];
    const float* c1p_wr = (const float*)d_in[10];
    const float* c1b_wl = (const float*)d_in[11];
    const float* c1b_bl = (const float*)d_in[12];
    const float* c1b_wr = (const float*)d_in[13];
    const float* c2p_wl = (const float*)d_in[14];
    const float* c2p_bl = (const float*)d_in[15];
    const float* c2p_wr = (const float*)d_in[16];
    const float* w_out  = (const float*)d_in[20];
    const float* b_out  = (const float*)d_in[21];

    const size_t NF = (size_t)N_NODES * H;
    float* bufA  = (float*)d_ws;
    float* bufU  = bufA + NF;
    float* agg   = bufU + NF;          // raw CSR scratch aliases agg (pre-gather only)
    u16*   fAb   = (u16*)(agg + NF);   // bf16 shadow of bufA (NF u16 = NF/2 floats)
    u16*   fUb   = fAb + NF;
    float* z     = (float*)(fUb + NF);
    float* headW = z + 2 * N_NODES;
    int* bh_p   = (int*)(headW + 512);
    int* bh_b   = bh_p + 2048;
    int* boff_p = bh_b + 2048;
    int* boff_b = boff_p + 2048;
    int* gcur_p = boff_b + 2048;
    int* gcur_b = gcur_p + 2048;
    int* off_p  = gcur_b + 2048;
    int* off_b  = off_p + OFFPAD;
    int* csr_p  = off_b + OFFPAD;
    int* csr_b  = csr_p + EDGES;
    u32* pa_h   = (u32*)(csr_b + EDGES);
    u32* pa_l   = pa_h + 10240;
    u32* pu_h   = pa_l + 10240;
    u32* pu_l   = pu_h + 2048;
    u32* pb_h   = pu_l + 2048;
    u32* pb_l   = pb_h + 4096;
    u32* pp_h   = pb_l + 4096;
    u32* pp_l   = pp_h + 4096;
    int* raw_p  = (int*)agg;
    int* raw_b  = raw_p + EDGES;

    const dim3 blk(256);
    const int grid_gemm = (N_NODES + 63) / 64;   // 1563

    // --- weight prep + head fold ---
    prep_weights<<<80, blk, 0, stream>>>(
        w_in_a, w_in_u, c1b_wl, c1b_wr, c1p_wl, c1p_wr,
        pa_h, pa_l, pu_h, pu_l, pb_h, pb_l, pp_h, pp_l);
    fold_head<<<1, blk, 0, stream>>>(w_out, c2p_wl, c2p_wr, c2p_bl, b_out, headW);

    // --- two-level counting sort ---
    hipMemsetAsync(bh_p, 0, 2 * 2048 * sizeof(int), stream);
    bucket_hist<<<2 * FILL_BLKS, blk, 0, stream>>>(ei_p, ei_b, bh_p, bh_b);
    scan_nbkt<<<2, blk, 0, stream>>>(bh_p, bh_b, boff_p, boff_b, gcur_p, gcur_b);
    sort_fill<<<2 * FILL_BLKS, blk, 0, stream>>>(ei_p, ei_b, gcur_p, gcur_b, raw_p, raw_b);
    bucket_sort2<<<2 * NBKT, blk, 0, stream>>>(
        raw_p, raw_b, boff_p, boff_b, off_p, off_b, csr_p, csr_b);

    // --- input projections (MFMA) ---
    proj_mfma<300, 320><<<grid_gemm, blk, 0, stream>>>(x_a, pa_h, pa_l, b_in_a, bufA, fAb);
    proj_mfma<64, 64>  <<<grid_gemm, blk, 0, stream>>>(x_u, pu_h, pu_l, b_in_u, bufU, fUb);

    // --- user side: agg article feats (bf16), sage -> z (u1 never stored) ---
    gather_bf16<<<25000, blk, 0, stream>>>(fAb, off_b, csr_b, agg);
    sage_mfma<true><<<grid_gemm, blk, 0, stream>>>(
        agg, bufU, pb_h, pb_l, c1b_bl, headW, z, nullptr);

    // --- article side: agg user feats (bf16), sage -> a1 in-place over bufA ---
    gather_bf16<<<25000, blk, 0, stream>>>(fUb, off_p, csr_p, agg);
    sage_mfma<false><<<grid_gemm, blk, 0, stream>>>(
        agg, bufA, pp_h, pp_l, c1p_bl, headW, nullptr, bufA);

    // --- final 2-dim aggregation + head ---
    final_head<<<25000, blk, 0, stream>>>(off_p, csr_p, z, bufA, headW, (float*)d_out);

    (void)in_sizes; (void)n_in; (void)out_size; (void)ws_size;
}